// Round 1
// baseline (10.185 us; speedup 1.0000x reference)
//
#include <hip/hip_runtime.h>
#include <math.h>

#define NXF 120
#define NYF 55
#define NTG 40
#define NPL 10
#define GCONST 10.72468f

// Reduced CompProbModel: the reference's final gathers [b_idx, tof] make all
// but one field location and one pass-duration row dead. We compute only the
// live slice: 40 ball-path cells x 10 players.
//
// Numerics discipline: every op feeding a discrete decision (int cast, rintf,
// comparison-adjacent value) uses __f*_rn intrinsics in the reference's exact
// evaluation order so -O3 cannot fma-contract or reassociate them.
__global__ void __launch_bounds__(64)
comp_prob_kernel(const float* __restrict__ frame,
                 const float* __restrict__ s_max_p,
                 const float* __restrict__ a_max_p,
                 const float* __restrict__ sigma_p,
                 const float* __restrict__ lam_off_p,
                 const float* __restrict__ lam_def_p,
                 float* __restrict__ out, int P)
{
    const int b = blockIdx.x;
    const float* fr = frame + b * P * 13;
    float* outb = out + b * P;

    __shared__ float T[NTG];
    __shared__ float rlocx[NPL], rlocy[NPL], rvx[NPL], rvy[NPL], lam_all[NPL];
    __shared__ float pnorm[NTG][NPL];
    __shared__ float all_t[NTG];
    __shared__ float shiftv[NTG];
    __shared__ int s_tof, s_bidx;
    __shared__ float s_ballx, s_bally;

    const int tid = threadIdx.x;
    const float s_max = s_max_p[0];
    const float a_max = a_max_p[0];
    const float sigma = sigma_p[0];
    const float reax  = __fdiv_rn(s_max, a_max);
    const float csig  = __fdiv_rn(3.14f, __fmul_rn(1.732f, sigma));

    // T_GRID = jnp.linspace(0.1, 4.0, 40, f32): start + i*delta, all f32.
    if (tid < NTG) {
        const float delta = __fdiv_rn(__fsub_rn(4.0f, 0.1f), 39.0f);
        T[tid] = __fadd_rn(0.1f, __fmul_rn((float)tid, delta));
    }
    if (tid < P) {
        const float x  = fr[tid*13+1], y  = fr[tid*13+2];
        const float vx = fr[tid*13+3], vy = fr[tid*13+4];
        const float ax = fr[tid*13+5], ay = fr[tid*13+6];
        const float tm = fr[tid*13+7];
        rvx[tid] = __fadd_rn(__fmul_rn(ax, reax), vx);
        rvy[tid] = __fadd_rn(__fmul_rn(ay, reax), vy);
        const float reax2 = __fmul_rn(reax, reax);
        const float xr = __fadd_rn(__fadd_rn(x, __fmul_rn(vx, reax)),
                                   __fmul_rn(__fmul_rn(0.5f, ax), reax2));
        const float yr = __fadd_rn(__fadd_rn(y, __fmul_rn(vy, reax)),
                                   __fmul_rn(__fmul_rn(0.5f, ay), reax2));
        rlocx[tid] = (float)(int)xr;   // astype(int32): trunc toward zero
        rlocy[tid] = (float)(int)yr;
        lam_all[tid] = __fadd_rn(__fmul_rn(lam_off_p[0], tm),
                                 __fmul_rn(lam_def_p[0], __fsub_rn(1.0f, tm)));
    }
    if (tid == 0) {
        int tof = (int)rintf(fr[12]) - 1;          // round-half-even, -1
        s_tof  = min(max(tof, 0), NTG - 1);        // jax gather clamps
        const int bx = (int)fr[10];                // frame[0,-3] = bex
        const int by = (int)fr[11];                // frame[0,-2] = bey
        s_bidx = min(max((by + 1) * NXF + bx, 0), NXF * NYF - 1);
        s_ballx = fr[8];
        s_bally = fr[9];
    }
    __syncthreads();

    const int s = s_tof;
    const float Ts = T[s];
    // FIELD_LOCS coords of the ball-end index
    const int bf = s_bidx;
    const float fx = __fadd_rn((float)(bf % NXF), 0.5f);
    const int byi = bf / NXF;
    const float fy = (byi == 0) ? -0.2f : __fsub_rn((float)byi, 0.5f);
    const float reachx = __fsub_rn(fx, s_ballx);
    const float reachy = __fsub_rn(fy, s_bally);
    const float vbx = __fdiv_rn(reachx, Ts);
    const float vby = __fdiv_rn(reachy, Ts);
    const float vz0s = __fmul_rn(__fmul_rn(Ts, GCONST), 0.5f);  // (T*G)/2

    if (tid < NTG) {
        const int t = tid;
        const float Tt = T[t];
        // ball trajectory cell: round(clip(ball + (reach/T[s])*T[t]))
        float valx = __fadd_rn(s_ballx, __fmul_rn(vbx, Tt));
        valx = fminf(fmaxf(valx, 0.0f), (float)(NXF - 1));
        const int txi = (int)rintf(valx);
        float valy = __fadd_rn(s_bally, __fmul_rn(vby, Tt));
        valy = fminf(fmaxf(valy, 0.0f), (float)(NYF - 1));
        const int tyi = (int)rintf(valy);
        const int pathf = tyi * NXF + txi;
        // z window: z = (2 + vz0[s]*T[t]) - (0.5*G)*(T[t]*T[t])
        const float z = __fsub_rn(__fadd_rn(2.0f, __fmul_rn(vz0s, Tt)),
                                  __fmul_rn(__fmul_rn(0.5f, GCONST),
                                            __fmul_rn(Tt, Tt)));
        const float lamz = (z < 3.0f && z > 0.0f) ? 1.0f : 0.0f;
        // tt_idx = round(10*T - 1)
        int tt = (int)rintf(__fsub_rn(__fmul_rn(10.0f, Tt), 1.0f));
        tt = min(max(tt, 0), NTG - 1);
        const float Ttt = T[tt];
        // field coords of the path cell
        const float pfx = __fadd_rn((float)(pathf % NXF), 0.5f);
        const int pyi = pathf / NXF;
        const float pfy = (pyi == 0) ? -0.2f : __fsub_rn((float)pyi, 0.5f);

        float ptraj[NPL];
        float ssum = 0.0f;
        #pragma unroll
        for (int p = 0; p < NPL; ++p) {
            const float dx = __fsub_rn(pfx, rlocx[p]);
            const float dy = __fsub_rn(pfy, rlocy[p]);
            const float dmag = __fsqrt_rn(__fadd_rn(__fmul_rn(dx, dx),
                                                    __fmul_rn(dy, dy)));
            const float dot = __fadd_rn(__fmul_rn(dx, rvx[p]),
                                        __fmul_rn(dy, rvy[p]));
            const float s0 = fminf(fmaxf(__fdiv_rn(dot, dmag), -s_max), s_max);
            float t_lt = __fdiv_rn(__fsub_rn(s_max, s0), a_max);
            float d_lt = __fmul_rn(__fmul_rn(t_lt, __fadd_rn(s0, s_max)), 0.5f);
            if (d_lt > dmag) {
                const float soa = __fdiv_rn(s0, a_max);
                t_lt = __fadd_rn(__fdiv_rn(-s0, a_max),
                                 __fsqrt_rn(__fadd_rn(__fmul_rn(soa, soa),
                                                      __fdiv_rn(__fmul_rn(2.0f, dmag), a_max))));
            }
            d_lt = fmaxf(fminf(d_lt, dmag), 0.0f);
            const float t_tot = __fadd_rn(__fadd_rn(reax, t_lt),
                                          __fdiv_rn(__fsub_rn(dmag, d_lt), s_max));
            const float arg = __fmul_rn(csig, __fsub_rn(Ttt, t_tot));
            const float pint = __fdiv_rn(1.0f, __fadd_rn(1.0f, expf(-arg)));
            const float pt = __fmul_rn(pint, lamz);
            ptraj[p] = pt;
            ssum = __fadd_rn(ssum, pt);
        }
        const float denom = fmaxf(1.0f, ssum);
        float at = 0.0f;
        #pragma unroll
        for (int p = 0; p < NPL; ++p) {
            const float pn = __fdiv_rn(ptraj[p], denom);
            pnorm[t][p] = pn;
            at = __fadd_rn(at, pn);
        }
        all_t[t] = at;
    }
    __syncthreads();

    if (tid == 0) {
        // remaining = cumprod(1 - all_t); shift = roll(remaining, 1) with
        // wraparound (shift[0] = remaining[39]); s==0 slice forced to 1.0.
        float rem[NTG];
        float r = 1.0f;
        for (int t = 0; t < NTG; ++t) {
            r = __fmul_rn(r, __fsub_rn(1.0f, all_t[t]));
            rem[t] = r;
        }
        for (int t = 0; t < NTG; ++t) {
            shiftv[t] = (s == 0) ? 1.0f : ((t == 0) ? rem[NTG - 1] : rem[t - 1]);
        }
    }
    __syncthreads();

    if (tid < P) {
        float acc = 0.0f;
        for (int t = 0; t <= s; ++t) {
            acc = __fadd_rn(acc, __fmul_rn(shiftv[t], pnorm[t][tid]));
        }
        outb[tid] = __fmul_rn(acc, lam_all[tid]);
    }
}

extern "C" void kernel_launch(void* const* d_in, const int* in_sizes, int n_in,
                              void* d_out, int out_size, void* d_ws, size_t ws_size,
                              hipStream_t stream) {
    const float* frame   = (const float*)d_in[0];
    const float* s_max   = (const float*)d_in[1];
    const float* a_max   = (const float*)d_in[2];
    const float* sigma   = (const float*)d_in[3];
    const float* lam_off = (const float*)d_in[4];
    const float* lam_def = (const float*)d_in[5];
    float* out = (float*)d_out;

    const int P = NPL;                 // setup_inputs: P = 10
    const int B = out_size / P;        // out shape (B, P)

    comp_prob_kernel<<<dim3(B), dim3(64), 0, stream>>>(
        frame, s_max, a_max, sigma, lam_off, lam_def, out, P);
}